// Round 1
// baseline (997.404 us; speedup 1.0000x reference)
//
#include <hip/hip_runtime.h>
#include <hip/hip_bf16.h>

#define N_NODES 50000
#define N_EDGES 800000
#define N_GRAPHS 512
#define DIM 256
#define LN_EPS 1e-5f

// -------------------- CSR build --------------------

__global__ void k_hist(const int* __restrict__ dst, int* __restrict__ cnt) {
    int e = blockIdx.x * blockDim.x + threadIdx.x;
    if (e < N_EDGES) atomicAdd(&cnt[dst[e]], 1);
}

__global__ void k_dinv(const int* __restrict__ cnt, float* __restrict__ dinv) {
    int n = blockIdx.x * blockDim.x + threadIdx.x;
    if (n < N_NODES) dinv[n] = rsqrtf((float)cnt[n] + 1.0f);
}

// 25 blocks x 256 threads x 8 elems = 51200 >= N
__global__ __launch_bounds__(256) void k_scan1(const int* __restrict__ cnt,
                                               int* __restrict__ row_ptr,
                                               int* __restrict__ bsum) {
    __shared__ int sd[256];
    int t = threadIdx.x, b = blockIdx.x;
    int base = b * 2048 + t * 8;
    int v[8];
    int tot = 0;
#pragma unroll
    for (int j = 0; j < 8; ++j) {
        int i = base + j;
        int c = (i < N_NODES) ? cnt[i] : 0;
        v[j] = tot;
        tot += c;
    }
    sd[t] = tot;
    __syncthreads();
    for (int off = 1; off < 256; off <<= 1) {
        int x = (t >= off) ? sd[t - off] : 0;
        __syncthreads();
        sd[t] += x;
        __syncthreads();
    }
    int excl = sd[t] - tot;
#pragma unroll
    for (int j = 0; j < 8; ++j) {
        int i = base + j;
        if (i < N_NODES) row_ptr[i] = excl + v[j];
    }
    if (t == 255) bsum[b] = sd[255];
}

__global__ void k_scan2(int* __restrict__ bsum, int nb) {
    if (threadIdx.x == 0 && blockIdx.x == 0) {
        int run = 0;
        for (int b = 0; b < nb; ++b) { int x = bsum[b]; bsum[b] = run; run += x; }
    }
}

__global__ void k_scan3(const int* __restrict__ bsum, int* __restrict__ row_ptr,
                        int* __restrict__ cursor) {
    int i = blockIdx.x * blockDim.x + threadIdx.x;
    if (i < N_NODES) {
        int v = row_ptr[i] + bsum[i >> 11];
        row_ptr[i] = v;
        cursor[i] = v;
    }
    if (i == 0) row_ptr[N_NODES] = N_EDGES;
}

__global__ void k_scatter(const int* __restrict__ src, const int* __restrict__ dst,
                          const float* __restrict__ dinv, int* __restrict__ cursor,
                          int* __restrict__ csr_src, float* __restrict__ csr_w) {
    int e = blockIdx.x * blockDim.x + threadIdx.x;
    if (e < N_EDGES) {
        int s = src[e], d = dst[e];
        int pos = atomicAdd(&cursor[d], 1);
        csr_src[pos] = s;
        csr_w[pos] = dinv[s] * dinv[d];
    }
}

// -------------------- fp32 GEMM: C[M x 256] = A[M x 256] @ W[256 x 256] --------------------
#define BM 64
#define BN 64
#define BK 16

__global__ __launch_bounds__(256) void k_gemm(const float* __restrict__ A,
                                              const float* __restrict__ W,
                                              float* __restrict__ C, int M) {
    __shared__ float As[BK][BM];
    __shared__ float Bs[BK][BN];
    int t = threadIdx.x;
    int bm0 = blockIdx.x * BM, bn0 = blockIdx.y * BN;
    int tm = t >> 4, tn = t & 15;
    float acc[4][4] = {};
    int arow = t >> 2, akq = t & 3;     // A loader: 64 rows x 4 float4
    int bkr = t >> 4, bcq = t & 15;     // B loader: 16 krows x 16 float4

    for (int k0 = 0; k0 < DIM; k0 += BK) {
        float4 a4 = make_float4(0.f, 0.f, 0.f, 0.f);
        int gr = bm0 + arow;
        if (gr < M) a4 = *(const float4*)&A[(size_t)gr * DIM + k0 + akq * 4];
        As[akq * 4 + 0][arow] = a4.x;
        As[akq * 4 + 1][arow] = a4.y;
        As[akq * 4 + 2][arow] = a4.z;
        As[akq * 4 + 3][arow] = a4.w;
        float4 b4 = *(const float4*)&W[(size_t)(k0 + bkr) * DIM + bn0 + bcq * 4];
        *(float4*)&Bs[bkr][bcq * 4] = b4;
        __syncthreads();
#pragma unroll
        for (int k = 0; k < BK; ++k) {
            float a[4], bb[4];
#pragma unroll
            for (int i = 0; i < 4; ++i) a[i] = As[k][tm * 4 + i];
#pragma unroll
            for (int j = 0; j < 4; ++j) bb[j] = Bs[k][tn * 4 + j];
#pragma unroll
            for (int i = 0; i < 4; ++i)
#pragma unroll
                for (int j = 0; j < 4; ++j) acc[i][j] += a[i] * bb[j];
        }
        __syncthreads();
    }
#pragma unroll
    for (int i = 0; i < 4; ++i) {
        int r = bm0 + tm * 4 + i;
        if (r < M) {
            float4 o = make_float4(acc[i][0], acc[i][1], acc[i][2], acc[i][3]);
            *(float4*)&C[(size_t)r * DIM + bn0 + tn * 4] = o;
        }
    }
}

// -------------------- aggregation + bias + LayerNorm + ReLU --------------------
// one block (256 threads) per node; thread d handles column d
__global__ __launch_bounds__(256) void k_agg_ln(const float* __restrict__ h,
                                                const int* __restrict__ row_ptr,
                                                const int* __restrict__ csr_src,
                                                const float* __restrict__ csr_w,
                                                const float* __restrict__ dinv,
                                                const float* __restrict__ bias,
                                                const float* __restrict__ gamma,
                                                const float* __restrict__ beta,
                                                float* __restrict__ out) {
    int n = blockIdx.x;
    int d = threadIdx.x;
    float di = dinv[n];
    float acc = h[(size_t)n * DIM + d] * di * di;   // self-loop: h[n]/deg[n]
    int e0 = row_ptr[n], e1 = row_ptr[n + 1];
    for (int e = e0; e < e1; ++e) {
        int s = csr_src[e];
        float w = csr_w[e];
        acc += w * h[(size_t)s * DIM + d];
    }
    float v = acc + bias[d];

    // LayerNorm over the 256 columns (4 waves)
    __shared__ float red1[4], red2[4];
    __shared__ float mu_s, rstd_s;
    float s1 = v, s2 = v * v;
#pragma unroll
    for (int off = 32; off >= 1; off >>= 1) {
        s1 += __shfl_down(s1, off);
        s2 += __shfl_down(s2, off);
    }
    int wid = d >> 6, lane = d & 63;
    if (lane == 0) { red1[wid] = s1; red2[wid] = s2; }
    __syncthreads();
    if (d == 0) {
        float a = red1[0] + red1[1] + red1[2] + red1[3];
        float b = red2[0] + red2[1] + red2[2] + red2[3];
        float mu = a * (1.0f / DIM);
        float var = b * (1.0f / DIM) - mu * mu;
        mu_s = mu;
        rstd_s = rsqrtf(var + LN_EPS);
    }
    __syncthreads();
    float y = (v - mu_s) * rstd_s * gamma[d] + beta[d];
    out[(size_t)n * DIM + d] = fmaxf(y, 0.0f);
}

// -------------------- pooling --------------------

__global__ void k_gbound(const int* __restrict__ batch, int* __restrict__ gstart) {
    int n = blockIdx.x * blockDim.x + threadIdx.x;
    if (n >= N_NODES) return;
    int bc = batch[n];
    int bp = (n == 0) ? -1 : batch[n - 1];
    for (int g = bp + 1; g <= bc; ++g) gstart[g] = n;
    if (n == N_NODES - 1)
        for (int g = bc + 1; g <= N_GRAPHS; ++g) gstart[g] = N_NODES;
}

__global__ __launch_bounds__(256) void k_pool(const float* __restrict__ x,
                                              const int* __restrict__ gstart,
                                              float* __restrict__ pooled) {
    int g = blockIdx.x, d = threadIdx.x;
    int r0 = gstart[g], r1 = gstart[g + 1];
    float s = 0.f;
    for (int r = r0; r < r1; ++r) s += x[(size_t)r * DIM + d];
    float c = (float)(r1 - r0);
    pooled[(size_t)g * DIM + d] = s / fmaxf(c, 1.0f);
}

// -------------------- final FC: out = relu(pooled @ fc_w^T + fc_b) --------------------
#define GB 16
__global__ __launch_bounds__(256) void k_fc(const float* __restrict__ pooled,
                                            const float* __restrict__ fcw,
                                            const float* __restrict__ fcb,
                                            float* __restrict__ out) {
    __shared__ float pl[GB][DIM];
    int j = threadIdx.x;
    int g0 = blockIdx.x * GB;
#pragma unroll
    for (int r = 0; r < GB; ++r) pl[r][j] = pooled[(size_t)(g0 + r) * DIM + j];
    __syncthreads();
    float acc[GB];
    float bj = fcb[j];
#pragma unroll
    for (int r = 0; r < GB; ++r) acc[r] = bj;
    for (int k = 0; k < DIM; ++k) {
        float w = fcw[(size_t)j * DIM + k];
#pragma unroll
        for (int r = 0; r < GB; ++r) acc[r] += pl[r][k] * w;
    }
#pragma unroll
    for (int r = 0; r < GB; ++r) out[(size_t)(g0 + r) * DIM + j] = fmaxf(acc[r], 0.0f);
}

// -------------------- launch --------------------

extern "C" void kernel_launch(void* const* d_in, const int* in_sizes, int n_in,
                              void* d_out, int out_size, void* d_ws, size_t ws_size,
                              hipStream_t stream) {
    const float* x = (const float*)d_in[0];
    const int* ei = (const int*)d_in[1];
    const int* src = ei;
    const int* dst = ei + N_EDGES;
    const int* batch = (const int*)d_in[2];
    const float* W[3] = {(const float*)d_in[3], (const float*)d_in[7], (const float*)d_in[11]};
    const float* bs[3] = {(const float*)d_in[4], (const float*)d_in[8], (const float*)d_in[12]};
    const float* gs[3] = {(const float*)d_in[5], (const float*)d_in[9], (const float*)d_in[13]};
    const float* be[3] = {(const float*)d_in[6], (const float*)d_in[10], (const float*)d_in[14]};
    const float* fcw = (const float*)d_in[15];
    const float* fcb = (const float*)d_in[16];
    float* out = (float*)d_out;

    // workspace carve-up
    char* p = (char*)d_ws;
    auto alloc = [&](size_t bytes) {
        char* r = p;
        p += (bytes + 255) & ~(size_t)255;
        return r;
    };
    float* h       = (float*)alloc((size_t)N_NODES * DIM * 4);
    float* xb      = (float*)alloc((size_t)N_NODES * DIM * 4);
    int*   cnt     = (int*)alloc((size_t)N_NODES * 4);
    int*   row_ptr = (int*)alloc((size_t)(N_NODES + 1) * 4);
    int*   cursor  = (int*)alloc((size_t)N_NODES * 4);
    float* dinv    = (float*)alloc((size_t)N_NODES * 4);
    int*   csr_src = (int*)alloc((size_t)N_EDGES * 4);
    float* csr_w   = (float*)alloc((size_t)N_EDGES * 4);
    int*   bsum    = (int*)alloc(256 * 4);
    int*   gstart  = (int*)alloc((size_t)(N_GRAPHS + 1) * 4);
    float* pooled  = (float*)alloc((size_t)N_GRAPHS * DIM * 4);

    hipMemsetAsync(cnt, 0, (size_t)N_NODES * 4, stream);

    const int TPB = 256;
    int gridE = (N_EDGES + TPB - 1) / TPB;
    int gridN = (N_NODES + TPB - 1) / TPB;
    const int NB1 = (N_NODES + 2047) / 2048;  // 25

    k_hist<<<gridE, TPB, 0, stream>>>(dst, cnt);
    k_dinv<<<gridN, TPB, 0, stream>>>(cnt, dinv);
    k_scan1<<<NB1, TPB, 0, stream>>>(cnt, row_ptr, bsum);
    k_scan2<<<1, 1, 0, stream>>>(bsum, NB1);
    k_scan3<<<gridN, TPB, 0, stream>>>(bsum, row_ptr, cursor);
    k_scatter<<<gridE, TPB, 0, stream>>>(src, dst, dinv, cursor, csr_src, csr_w);

    const float* cur = x;
    for (int l = 0; l < 3; ++l) {
        dim3 gg((N_NODES + BM - 1) / BM, DIM / BN);
        k_gemm<<<gg, TPB, 0, stream>>>(cur, W[l], h, N_NODES);
        k_agg_ln<<<N_NODES, TPB, 0, stream>>>(h, row_ptr, csr_src, csr_w, dinv,
                                              bs[l], gs[l], be[l], xb);
        cur = xb;
    }

    k_gbound<<<gridN, TPB, 0, stream>>>(batch, gstart);
    k_pool<<<N_GRAPHS, TPB, 0, stream>>>(xb, gstart, pooled);
    k_fc<<<N_GRAPHS / GB, TPB, 0, stream>>>(pooled, fcw, fcb, out);
}

// Round 2
// 471.743 us; speedup vs baseline: 2.1143x; 2.1143x over previous
//
#include <hip/hip_runtime.h>
#include <hip/hip_bf16.h>

#define N_NODES 50000
#define N_EDGES 800000
#define N_GRAPHS 512
#define DIM 256
#define LN_EPS 1e-5f

typedef __attribute__((ext_vector_type(8))) short bf16x8;
typedef __attribute__((ext_vector_type(4))) float f32x4;
typedef __attribute__((ext_vector_type(8))) ushort ushort8;

__device__ __forceinline__ float bf2f(ushort u) {
    union { float f; unsigned int i; } c;
    c.i = ((unsigned int)u) << 16;
    return c.f;
}
__device__ __forceinline__ ushort f2bf(float f) {
    union { float f; unsigned int i; } c;
    c.f = f;
    unsigned int r = (c.i + 0x7fffu + ((c.i >> 16) & 1u)) >> 16;
    return (ushort)r;
}
__device__ __forceinline__ float4 b2f4(ushort4 v) {
    return make_float4(bf2f(v.x), bf2f(v.y), bf2f(v.z), bf2f(v.w));
}

// -------------------- CSR build --------------------

__global__ void k_hist(const int* __restrict__ dst, int* __restrict__ cnt) {
    int e = blockIdx.x * blockDim.x + threadIdx.x;
    if (e < N_EDGES) atomicAdd(&cnt[dst[e]], 1);
}

__global__ void k_dinv(const int* __restrict__ cnt, float* __restrict__ dinv) {
    int n = blockIdx.x * blockDim.x + threadIdx.x;
    if (n < N_NODES) dinv[n] = rsqrtf((float)cnt[n] + 1.0f);
}

__global__ __launch_bounds__(256) void k_scan1(const int* __restrict__ cnt,
                                               int* __restrict__ row_ptr,
                                               int* __restrict__ bsum) {
    __shared__ int sd[256];
    int t = threadIdx.x, b = blockIdx.x;
    int base = b * 2048 + t * 8;
    int v[8];
    int tot = 0;
#pragma unroll
    for (int j = 0; j < 8; ++j) {
        int i = base + j;
        int c = (i < N_NODES) ? cnt[i] : 0;
        v[j] = tot;
        tot += c;
    }
    sd[t] = tot;
    __syncthreads();
    for (int off = 1; off < 256; off <<= 1) {
        int x = (t >= off) ? sd[t - off] : 0;
        __syncthreads();
        sd[t] += x;
        __syncthreads();
    }
    int excl = sd[t] - tot;
#pragma unroll
    for (int j = 0; j < 8; ++j) {
        int i = base + j;
        if (i < N_NODES) row_ptr[i] = excl + v[j];
    }
    if (t == 255) bsum[b] = sd[255];
}

__global__ void k_scan2(int* __restrict__ bsum, int nb) {
    if (threadIdx.x == 0 && blockIdx.x == 0) {
        int run = 0;
        for (int b = 0; b < nb; ++b) { int x = bsum[b]; bsum[b] = run; run += x; }
    }
}

__global__ void k_scan3(const int* __restrict__ bsum, int* __restrict__ row_ptr,
                        int* __restrict__ cursor) {
    int i = blockIdx.x * blockDim.x + threadIdx.x;
    if (i < N_NODES) {
        int v = row_ptr[i] + bsum[i >> 11];
        row_ptr[i] = v;
        cursor[i] = v;
    }
    if (i == 0) row_ptr[N_NODES] = N_EDGES;
}

__global__ void k_scatter(const int* __restrict__ src, const int* __restrict__ dst,
                          const float* __restrict__ dinv, int* __restrict__ cursor,
                          int* __restrict__ csr_src, float* __restrict__ csr_w) {
    int e = blockIdx.x * blockDim.x + threadIdx.x;
    if (e < N_EDGES) {
        int s = src[e], d = dst[e];
        int pos = atomicAdd(&cursor[d], 1);
        csr_src[pos] = s;
        csr_w[pos] = dinv[s] * dinv[d];
    }
}

// -------------------- weight transpose + bf16 cast: Wt[n][k] = bf16(W[k][n]) --------------------

__global__ __launch_bounds__(256) void k_wt(const float* __restrict__ W, ushort* __restrict__ Wt) {
    int t = threadIdx.x;
    int kbase = blockIdx.x * 16;
    for (int kk = 0; kk < 16; ++kk) {
        int k = kbase + kk;
        Wt[(size_t)t * DIM + k] = f2bf(W[(size_t)k * DIM + t]);
    }
}

// -------------------- fp32 -> bf16 convert --------------------

__global__ __launch_bounds__(256) void k_xcvt(const float* __restrict__ x, ushort* __restrict__ o) {
    int i = blockIdx.x * blockDim.x + threadIdx.x;  // one float4 per thread
    const size_t total4 = (size_t)N_NODES * DIM / 4;
    if ((size_t)i < total4) {
        float4 v = *(const float4*)(x + (size_t)i * 4);
        ushort4 u;
        u.x = f2bf(v.x); u.y = f2bf(v.y); u.z = f2bf(v.z); u.w = f2bf(v.w);
        *(ushort4*)(o + (size_t)i * 4) = u;
    }
}

// -------------------- bf16 MFMA GEMM: h[M x 256] = A[M x 256] @ W[256 x 256] --------------------
// A in bf16 row-major, Wt in bf16 [n][k] (W transposed). Output h in bf16.
// Block: 256 threads = 4 waves (2x2), tile 128x128, BK=32.

#define GBM 128
#define GBN 128
#define GBK 32
#define LDSP 40  // padded row stride (ushorts): 80B, 16B-aligned, 2-way bank alias (free)

__global__ __launch_bounds__(256) void k_gemm(const ushort* __restrict__ A,
                                              const ushort* __restrict__ Wt,
                                              ushort* __restrict__ H, int M) {
    __shared__ ushort As[GBM][LDSP];
    __shared__ ushort Bs[GBN][LDSP];
    int t = threadIdx.x;
    int lane = t & 63;
    int wid = t >> 6;
    int wm = wid >> 1, wn = wid & 1;
    int bm0 = blockIdx.x * GBM, bn0 = blockIdx.y * GBN;

    f32x4 acc[4][4];
#pragma unroll
    for (int m = 0; m < 4; ++m)
#pragma unroll
        for (int n = 0; n < 4; ++n) acc[m][n] = (f32x4)0.0f;

    int fr = lane & 15;          // fragment row/col within 16
    int fq = lane >> 4;          // k-group (0..3) -> k offset 8*fq
    for (int k0 = 0; k0 < DIM; k0 += GBK) {
        // stage A and B tiles: 128 rows x 32 bf16 (64B) each
#pragma unroll
        for (int p = 0; p < 2; ++p) {
            int i = t + p * 256;          // 0..511
            int r = i >> 2, q = i & 3;    // row, 16B chunk
            int grow = bm0 + r;
            ushort8 va = {};
            if (grow < M) va = *(const ushort8*)(A + (size_t)grow * DIM + k0 + q * 8);
            *(ushort8*)&As[r][q * 8] = va;
            ushort8 vb = *(const ushort8*)(Wt + (size_t)(bn0 + r) * DIM + k0 + q * 8);
            *(ushort8*)&Bs[r][q * 8] = vb;
        }
        __syncthreads();
        bf16x8 af[4], bfv[4];
#pragma unroll
        for (int m = 0; m < 4; ++m)
            af[m] = *(const bf16x8*)&As[wm * 64 + m * 16 + fr][fq * 8];
#pragma unroll
        for (int n = 0; n < 4; ++n)
            bfv[n] = *(const bf16x8*)&Bs[wn * 64 + n * 16 + fr][fq * 8];
#pragma unroll
        for (int m = 0; m < 4; ++m)
#pragma unroll
            for (int n = 0; n < 4; ++n)
                acc[m][n] = __builtin_amdgcn_mfma_f32_16x16x32_bf16(af[m], bfv[n], acc[m][n], 0, 0, 0);
        __syncthreads();
    }
    // epilogue: D row = (lane>>4)*4 + j, col = lane&15  [m89-verified]
#pragma unroll
    for (int m = 0; m < 4; ++m) {
        int row0 = bm0 + wm * 64 + m * 16 + fq * 4;
#pragma unroll
        for (int n = 0; n < 4; ++n) {
            int col = bn0 + wn * 64 + n * 16 + fr;
#pragma unroll
            for (int j = 0; j < 4; ++j) {
                int row = row0 + j;
                if (row < M) H[(size_t)row * DIM + col] = f2bf(acc[m][n][j]);
            }
        }
    }
}

// -------------------- aggregation + bias + LayerNorm + ReLU (bf16 in/out) --------------------
// 1 wave per node, 4 nodes per block, 4 cols per lane, edge loop unrolled x4.

#define FMA4(A, W, V) { float4 _f = b2f4(V); A.x += (W)*_f.x; A.y += (W)*_f.y; A.z += (W)*_f.z; A.w += (W)*_f.w; }

__global__ __launch_bounds__(256) void k_agg_ln(const ushort* __restrict__ h,
                                                const int* __restrict__ rp,
                                                const int* __restrict__ cs,
                                                const float* __restrict__ cw,
                                                const float* __restrict__ dinv,
                                                const float* __restrict__ bias,
                                                const float* __restrict__ gamma,
                                                const float* __restrict__ beta,
                                                ushort* __restrict__ out) {
    int node = (blockIdx.x << 2) + (threadIdx.x >> 6);
    int lane = threadIdx.x & 63;
    int c0 = lane << 2;

    float di = dinv[node];
    float sw = di * di;
    ushort4 hv = *(const ushort4*)(h + (size_t)node * DIM + c0);
    float4 a0 = b2f4(hv);
    a0.x *= sw; a0.y *= sw; a0.z *= sw; a0.w *= sw;
    float4 a1 = make_float4(0.f, 0.f, 0.f, 0.f);
    float4 a2 = a1, a3 = a1;

    int e0 = rp[node], e1 = rp[node + 1];
    for (int e = e0; e < e1; e += 4) {
        int s0 = cs[e];
        float w0 = cw[e];
        int s1 = 0, s2 = 0, s3 = 0;
        float w1 = 0.f, w2 = 0.f, w3 = 0.f;
        if (e + 1 < e1) { s1 = cs[e + 1]; w1 = cw[e + 1]; }
        if (e + 2 < e1) { s2 = cs[e + 2]; w2 = cw[e + 2]; }
        if (e + 3 < e1) { s3 = cs[e + 3]; w3 = cw[e + 3]; }
        ushort4 v0 = *(const ushort4*)(h + (size_t)s0 * DIM + c0);
        ushort4 v1 = *(const ushort4*)(h + (size_t)s1 * DIM + c0);
        ushort4 v2 = *(const ushort4*)(h + (size_t)s2 * DIM + c0);
        ushort4 v3 = *(const ushort4*)(h + (size_t)s3 * DIM + c0);
        FMA4(a0, w0, v0);
        FMA4(a1, w1, v1);
        FMA4(a2, w2, v2);
        FMA4(a3, w3, v3);
    }

    float4 bi = *(const float4*)(bias + c0);
    float4 v;
    v.x = a0.x + a1.x + a2.x + a3.x + bi.x;
    v.y = a0.y + a1.y + a2.y + a3.y + bi.y;
    v.z = a0.z + a1.z + a2.z + a3.z + bi.z;
    v.w = a0.w + a1.w + a2.w + a3.w + bi.w;

    float s1v = v.x + v.y + v.z + v.w;
    float s2v = v.x * v.x + v.y * v.y + v.z * v.z + v.w * v.w;
#pragma unroll
    for (int off = 1; off < 64; off <<= 1) {
        s1v += __shfl_xor(s1v, off);
        s2v += __shfl_xor(s2v, off);
    }
    float mu = s1v * (1.0f / DIM);
    float var = s2v * (1.0f / DIM) - mu * mu;
    float rstd = rsqrtf(var + LN_EPS);

    float4 g = *(const float4*)(gamma + c0);
    float4 be = *(const float4*)(beta + c0);
    ushort4 o;
    o.x = f2bf(fmaxf((v.x - mu) * rstd * g.x + be.x, 0.f));
    o.y = f2bf(fmaxf((v.y - mu) * rstd * g.y + be.y, 0.f));
    o.z = f2bf(fmaxf((v.z - mu) * rstd * g.z + be.z, 0.f));
    o.w = f2bf(fmaxf((v.w - mu) * rstd * g.w + be.w, 0.f));
    *(ushort4*)(out + (size_t)node * DIM + c0) = o;
}

// -------------------- pooling --------------------

__global__ void k_gbound(const int* __restrict__ batch, int* __restrict__ gstart) {
    int n = blockIdx.x * blockDim.x + threadIdx.x;
    if (n >= N_NODES) return;
    int bc = batch[n];
    int bp = (n == 0) ? -1 : batch[n - 1];
    for (int g = bp + 1; g <= bc; ++g) gstart[g] = n;
    if (n == N_NODES - 1)
        for (int g = bc + 1; g <= N_GRAPHS; ++g) gstart[g] = N_NODES;
}

__global__ __launch_bounds__(256) void k_pool(const ushort* __restrict__ x,
                                              const int* __restrict__ gstart,
                                              float* __restrict__ pooled) {
    int g = blockIdx.x, d = threadIdx.x;
    int r0 = gstart[g], r1 = gstart[g + 1];
    float s = 0.f;
    for (int r = r0; r < r1; ++r) s += bf2f(x[(size_t)r * DIM + d]);
    float c = (float)(r1 - r0);
    pooled[(size_t)g * DIM + d] = s / fmaxf(c, 1.0f);
}

// -------------------- final FC: out = relu(pooled @ fc_w^T + fc_b) --------------------
#define GB 16
__global__ __launch_bounds__(256) void k_fc(const float* __restrict__ pooled,
                                            const float* __restrict__ fcw,
                                            const float* __restrict__ fcb,
                                            float* __restrict__ out) {
    __shared__ float pl[GB][DIM];
    int j = threadIdx.x;
    int g0 = blockIdx.x * GB;
#pragma unroll
    for (int r = 0; r < GB; ++r) pl[r][j] = pooled[(size_t)(g0 + r) * DIM + j];
    __syncthreads();
    float acc[GB];
    float bj = fcb[j];
#pragma unroll
    for (int r = 0; r < GB; ++r) acc[r] = bj;
    for (int k = 0; k < DIM; ++k) {
        float w = fcw[(size_t)j * DIM + k];
#pragma unroll
        for (int r = 0; r < GB; ++r) acc[r] += pl[r][k] * w;
    }
#pragma unroll
    for (int r = 0; r < GB; ++r) out[(size_t)(g0 + r) * DIM + j] = fmaxf(acc[r], 0.0f);
}

// -------------------- launch --------------------

extern "C" void kernel_launch(void* const* d_in, const int* in_sizes, int n_in,
                              void* d_out, int out_size, void* d_ws, size_t ws_size,
                              hipStream_t stream) {
    const float* x = (const float*)d_in[0];
    const int* ei = (const int*)d_in[1];
    const int* src = ei;
    const int* dst = ei + N_EDGES;
    const int* batch = (const int*)d_in[2];
    const float* W[3] = {(const float*)d_in[3], (const float*)d_in[7], (const float*)d_in[11]};
    const float* bs[3] = {(const float*)d_in[4], (const float*)d_in[8], (const float*)d_in[12]};
    const float* gs[3] = {(const float*)d_in[5], (const float*)d_in[9], (const float*)d_in[13]};
    const float* be[3] = {(const float*)d_in[6], (const float*)d_in[10], (const float*)d_in[14]};
    const float* fcw = (const float*)d_in[15];
    const float* fcb = (const float*)d_in[16];
    float* out = (float*)d_out;

    char* p = (char*)d_ws;
    auto alloc = [&](size_t bytes) {
        char* r = p;
        p += (bytes + 255) & ~(size_t)255;
        return r;
    };
    ushort* h       = (ushort*)alloc((size_t)N_NODES * DIM * 2);
    ushort* bufA    = (ushort*)alloc((size_t)N_NODES * DIM * 2);
    ushort* bufB    = (ushort*)alloc((size_t)N_NODES * DIM * 2);
    ushort* Wt[3];
    for (int l = 0; l < 3; ++l) Wt[l] = (ushort*)alloc((size_t)DIM * DIM * 2);
    int*   cnt     = (int*)alloc((size_t)N_NODES * 4);
    int*   row_ptr = (int*)alloc((size_t)(N_NODES + 1) * 4);
    int*   cursor  = (int*)alloc((size_t)N_NODES * 4);
    float* dinv    = (float*)alloc((size_t)N_NODES * 4);
    int*   csr_src = (int*)alloc((size_t)N_EDGES * 4);
    float* csr_w   = (float*)alloc((size_t)N_EDGES * 4);
    int*   bsum    = (int*)alloc(256 * 4);
    int*   gstart  = (int*)alloc((size_t)(N_GRAPHS + 1) * 4);
    float* pooled  = (float*)alloc((size_t)N_GRAPHS * DIM * 4);

    hipMemsetAsync(cnt, 0, (size_t)N_NODES * 4, stream);

    const int TPB = 256;
    int gridE = (N_EDGES + TPB - 1) / TPB;
    int gridN = (N_NODES + TPB - 1) / TPB;
    const int NB1 = (N_NODES + 2047) / 2048;  // 25

    for (int l = 0; l < 3; ++l) k_wt<<<16, TPB, 0, stream>>>(W[l], Wt[l]);
    {
        int tot4 = N_NODES * DIM / 4;
        k_xcvt<<<(tot4 + TPB - 1) / TPB, TPB, 0, stream>>>(x, bufA);
    }

    k_hist<<<gridE, TPB, 0, stream>>>(dst, cnt);
    k_dinv<<<gridN, TPB, 0, stream>>>(cnt, dinv);
    k_scan1<<<NB1, TPB, 0, stream>>>(cnt, row_ptr, bsum);
    k_scan2<<<1, 1, 0, stream>>>(bsum, NB1);
    k_scan3<<<gridN, TPB, 0, stream>>>(bsum, row_ptr, cursor);
    k_scatter<<<gridE, TPB, 0, stream>>>(src, dst, dinv, cursor, csr_src, csr_w);

    ushort* cur = bufA;
    ushort* nxt = bufB;
    for (int l = 0; l < 3; ++l) {
        dim3 gg((N_NODES + GBM - 1) / GBM, DIM / GBN);
        k_gemm<<<gg, TPB, 0, stream>>>(cur, Wt[l], h, N_NODES);
        k_agg_ln<<<N_NODES / 4, TPB, 0, stream>>>(h, row_ptr, csr_src, csr_w, dinv,
                                                  bs[l], gs[l], be[l], nxt);
        ushort* tmp = cur; cur = nxt; nxt = tmp;
    }

    k_gbound<<<gridN, TPB, 0, stream>>>(batch, gstart);
    k_pool<<<N_GRAPHS, TPB, 0, stream>>>(cur, gstart, pooled);
    k_fc<<<N_GRAPHS / GB, TPB, 0, stream>>>(pooled, fcw, fcb, out);
}